// Round 1
// baseline (441.079 us; speedup 1.0000x reference)
//
#include <hip/hip_runtime.h>

// InnerShiftTriple: bz=4, c=512 (c2=256), h=w=64 (hw=4096), fp32 in/out, int32 mask.
// out = concat([former, latter, shifted]) where shifted[i] = former[argmax_j sim(i,j)]
// for masked i over non-masked keys j, cosine sim of "latter" features.

#define HW 4096
#define C2 256
#define BZd 4
#define TQ 16

__device__ __forceinline__ unsigned ordf(float f) {
  // monotone float->uint mapping (no NaNs possible here)
  unsigned u = __float_as_uint(f);
  return (u & 0x80000000u) ? ~u : (u | 0x80000000u);
}

// --- K1: per-pixel denom = sqrt(sum_c latter^2) + 1e-8 -----------------------
__global__ void norm_kernel(const float* __restrict__ in, float* __restrict__ denom) {
  int idx = blockIdx.x * 256 + threadIdx.x;     // [0, 16384)
  int b = idx >> 12, j = idx & (HW - 1);
  const float* p = in + ((size_t)b * 512 + C2) * HW + j;
  float ss = 0.f;
#pragma unroll 8
  for (int c = 0; c < C2; ++c) { float v = p[(size_t)c * HW]; ss = fmaf(v, v, ss); }
  denom[idx] = sqrtf(ss) + 1e-8f;
}

// --- K2: ordered compaction of masked (query) / known (key) pixel indices ----
__global__ void scan_kernel(const int* __restrict__ mask, int* __restrict__ qcnt,
                            int* __restrict__ kcnt, int* __restrict__ qlist,
                            int* __restrict__ klist, int* __restrict__ srcmap) {
  int b = blockIdx.x, t = threadIdx.x;
  const int* m = mask + b * HW;
  int base = t * 16;
  int fl = 0, cq = 0;
#pragma unroll
  for (int i = 0; i < 16; ++i) { int f = (m[base + i] >= 1); fl |= f << i; cq += f; }
  __shared__ int s[256];
  s[t] = cq; __syncthreads();
  for (int off = 1; off < 256; off <<= 1) {
    int v = (t >= off) ? s[t - off] : 0;
    __syncthreads(); s[t] += v; __syncthreads();
  }
  int total = s[255];
  int qp = s[t] - cq;      // exclusive prefix of masked count
  int kp = base - qp;      // exclusive prefix of known count
  for (int i = 0; i < 16; ++i) {
    int j = base + i;
    if ((fl >> i) & 1) qlist[b * HW + qp++] = j;
    else               klist[b * HW + kp++] = j;
    srcmap[b * HW + j] = -1;
  }
  if (t == 0) { qcnt[b] = total; kcnt[b] = HW - total; }
}

// --- K3: pack normalized latter features for compacted keys & queries --------
__global__ void pack_kernel(const float* __restrict__ in, const float* __restrict__ denom,
                            const int* __restrict__ qcnt, const int* __restrict__ kcnt,
                            const int* __restrict__ qlist, const int* __restrict__ klist,
                            float* __restrict__ qpack, float* __restrict__ kpack) {
  int jj = blockIdx.x * 256 + threadIdx.x;   // packed position [0,4096)
  int c = blockIdx.y, b = blockIdx.z;
  const float* lat = in + ((size_t)b * 512 + C2 + c) * HW;
  const float* dn = denom + b * HW;
  float kv = 0.f;
  if (jj < kcnt[b]) { int j = klist[b * HW + jj]; kv = lat[j] / dn[j]; }
  kpack[((size_t)b * C2 + c) * HW + jj] = kv;  // zero-padded past kcnt
  if (jj < qcnt[b]) { int j = qlist[b * HW + jj]; qpack[((size_t)b * C2 + c) * HW + jj] = lat[j] / dn[j]; }
}

// --- K4: passthrough copy of channels [0,512) into out -----------------------
__global__ void copy_kernel(const float4* __restrict__ in, float* __restrict__ out) {
  size_t idx = (size_t)blockIdx.x * 256 + threadIdx.x;  // 2^21 float4s
  int b = (int)(idx >> 19);                              // 2^19 float4 per batch
  size_t r = idx & 524287;
  float4 v = in[((size_t)b << 19) + r];
  ((float4*)(out + (size_t)b * 768 * HW))[r] = v;
}

// --- K5: fused GEMM + argmax. Block: 16 queries (LDS) x all keys, 4 keys/thread.
__global__ __launch_bounds__(256) void argmax_kernel(
    const float* __restrict__ qpack, const float* __restrict__ kpack,
    const int* __restrict__ qcnt, const int* __restrict__ kcnt,
    const int* __restrict__ qlist, const int* __restrict__ klist,
    int* __restrict__ srcmap) {
  int b = blockIdx.y;
  int qstart = blockIdx.x * TQ;
  int nq_tot = qcnt[b];
  if (qstart >= nq_tot) return;
  int nq = min(TQ, nq_tot - qstart);
  int kc = kcnt[b];
  int t = threadIdx.x;

  __shared__ float qt_s[C2][TQ];     // [c][q], 16 KB; row = 64 B
  {
    int q = t & (TQ - 1), cr = t >> 4;
    const float* qp = qpack + (size_t)b * C2 * HW + qstart + q;
#pragma unroll
    for (int p = 0; p < 16; ++p) {
      int c = p * 16 + cr;
      qt_s[c][q] = (q < nq) ? qp[(size_t)c * HW] : 0.f;
    }
  }
  __syncthreads();

  const float* kp = kpack + (size_t)b * C2 * HW;
  unsigned long long best[TQ];
#pragma unroll
  for (int q = 0; q < TQ; ++q) best[q] = 0ull;

  int nchunks = (kc + 1023) >> 10;   // 1024 keys per chunk (4 per thread)
  for (int ch = 0; ch < nchunks; ++ch) {
    int kk0 = (ch << 10) + t;
    float acc[4][TQ];
#pragma unroll
    for (int kr = 0; kr < 4; ++kr)
#pragma unroll
      for (int q = 0; q < TQ; ++q) acc[kr][q] = 0.f;
    const float* kcol = kp + kk0;
    for (int c = 0; c < C2; ++c) {
      float kv[4];
#pragma unroll
      for (int kr = 0; kr < 4; ++kr) kv[kr] = kcol[(size_t)c * HW + (kr << 8)];
      float qv[TQ];
#pragma unroll
      for (int qq = 0; qq < TQ; qq += 4) {
        float4 f = *(const float4*)&qt_s[c][qq];   // broadcast ds_read_b128
        qv[qq] = f.x; qv[qq + 1] = f.y; qv[qq + 2] = f.z; qv[qq + 3] = f.w;
      }
#pragma unroll
      for (int kr = 0; kr < 4; ++kr)
#pragma unroll
        for (int q = 0; q < TQ; ++q)
          acc[kr][q] = fmaf(kv[kr], qv[q], acc[kr][q]);
    }
#pragma unroll
    for (int kr = 0; kr < 4; ++kr) {
      int kk = kk0 + (kr << 8);
      if (kk < kc) {
#pragma unroll
        for (int q = 0; q < TQ; ++q) {
          // pack: higher value wins; equal value -> lower packed index wins
          unsigned long long pk =
              ((unsigned long long)ordf(acc[kr][q]) << 32) | (unsigned)(0xFFFFFFFFu - (unsigned)kk);
          if (pk > best[q]) best[q] = pk;
        }
      }
    }
  }

  // reduce (max of packed u64) across 256 threads
  __shared__ unsigned long long part[4][TQ];
  int lane = t & 63, wid = t >> 6;
#pragma unroll
  for (int q = 0; q < TQ; ++q) {
    unsigned long long v = best[q];
    for (int off = 32; off >= 1; off >>= 1) {
      unsigned long long o = __shfl_down(v, (unsigned)off, 64);
      if (o > v) v = o;
    }
    if (lane == 0) part[wid][q] = v;
  }
  __syncthreads();
  if (t < TQ && t < nq) {
    unsigned long long v = part[0][t];
#pragma unroll
    for (int w = 1; w < 4; ++w) if (part[w][t] > v) v = part[w][t];
    int kk = (int)(0xFFFFFFFFu - (unsigned)(v & 0xFFFFFFFFull));
    int oj = klist[b * HW + kk];                 // original key index
    int oi = qlist[b * HW + qstart + t];         // original query index
    srcmap[b * HW + oi] = oj;
  }
}

// --- K6: shifted channels: coalesced writes, L1-local gathers ----------------
__global__ void gather_kernel(const float* __restrict__ in, const int* __restrict__ srcmap,
                              float* __restrict__ out) {
  int idx = blockIdx.x * 256 + threadIdx.x;   // 4*256*4096 = 2^22
  int j = idx & (HW - 1);
  int c = (idx >> 12) & 255;
  int b = idx >> 20;
  int s = srcmap[b * HW + j];
  float v = (s >= 0) ? in[((size_t)b * 512 + c) * HW + s] : 0.f;
  out[((size_t)b * 768 + 512 + c) * HW + j] = v;
}

extern "C" void kernel_launch(void* const* d_in, const int* in_sizes, int n_in,
                              void* d_out, int out_size, void* d_ws, size_t ws_size,
                              hipStream_t stream) {
  const float* in = (const float*)d_in[0];
  const int* mask = (const int*)d_in[1];
  float* out = (float*)d_out;

  // workspace layout (~33.8 MB total)
  float* denom = (float*)d_ws;                    // 4*4096 f32
  int* qcnt = (int*)(denom + BZd * HW);           // 4
  int* kcnt = qcnt + BZd;                         // 4
  int* qlist = kcnt + BZd;                        // 4*4096
  int* klist = qlist + BZd * HW;                  // 4*4096
  int* srcmap = klist + BZd * HW;                 // 4*4096
  float* kpack = (float*)(srcmap + BZd * HW);     // 4*256*4096 f32
  float* qpack = kpack + (size_t)BZd * C2 * HW;   // 4*256*4096 f32

  hipLaunchKernelGGL(norm_kernel, dim3(BZd * HW / 256), dim3(256), 0, stream, in, denom);
  hipLaunchKernelGGL(scan_kernel, dim3(BZd), dim3(256), 0, stream,
                     mask, qcnt, kcnt, qlist, klist, srcmap);
  hipLaunchKernelGGL(pack_kernel, dim3(HW / 256, C2, BZd), dim3(256), 0, stream,
                     in, denom, qcnt, kcnt, qlist, klist, qpack, kpack);
  hipLaunchKernelGGL(copy_kernel, dim3(BZd * 512 * HW / 4 / 256), dim3(256), 0, stream,
                     (const float4*)in, out);
  hipLaunchKernelGGL(argmax_kernel, dim3(HW / TQ, BZd), dim3(256), 0, stream,
                     qpack, kpack, qcnt, kcnt, qlist, klist, srcmap);
  hipLaunchKernelGGL(gather_kernel, dim3(BZd * C2 * HW / 256), dim3(256), 0, stream,
                     in, srcmap, out);
}

// Round 2
// 370.968 us; speedup vs baseline: 1.1890x; 1.1890x over previous
//
#include <hip/hip_runtime.h>

// InnerShiftTriple: bz=4, c=512 (c2=256), h=w=64 (hw=4096), fp32 in/out, int32 mask.
// out = concat([former, latter, shifted]); shifted[i] = former[argmax_j sim(i,j)]
// for masked i over non-masked keys j, cosine sim of "latter" features.
// Argmax is invariant to query normalization -> only keys are normalized.

#define HW 4096
#define C2 256
#define BZd 4
#define TQ 16
#define NK 8          // keys per thread in pass1
#define BT 128        // pass1 block threads; BT*NK = 1024 keys per slice

__device__ __forceinline__ unsigned ordf(float f) {
  unsigned u = __float_as_uint(f);
  return (u & 0x80000000u) ? ~u : (u | 0x80000000u);
}

__device__ __forceinline__ unsigned long long shfl_down_u64(unsigned long long v, int off) {
  unsigned lo = (unsigned)v, hi = (unsigned)(v >> 32);
  lo = __shfl_down(lo, off, 64);
  hi = __shfl_down(hi, off, 64);
  return ((unsigned long long)hi << 32) | lo;
}

// --- K1: per-pixel inv-norm = 1/(sqrt(sum_c latter^2)+1e-8) ------------------
__global__ void inv_kernel(const float* __restrict__ in, float* __restrict__ inv) {
  int idx = blockIdx.x * 256 + threadIdx.x;     // [0, 16384)
  int b = idx >> 12, j = idx & (HW - 1);
  const float* p = in + ((size_t)b * 512 + C2) * HW + j;
  float ss = 0.f;
#pragma unroll 8
  for (int c = 0; c < C2; ++c) { float v = p[(size_t)c * HW]; ss = fmaf(v, v, ss); }
  inv[idx] = 1.0f / (sqrtf(ss) + 1e-8f);
}

// --- K2: ordered compaction of masked (query) / known (key) pixel indices ----
__global__ void scan_kernel(const int* __restrict__ mask, int* __restrict__ qcnt,
                            int* __restrict__ kcnt, int* __restrict__ qlist,
                            int* __restrict__ klist, int* __restrict__ srcmap) {
  int b = blockIdx.x, t = threadIdx.x;
  const int* m = mask + b * HW;
  int base = t * 16;
  int fl = 0, cq = 0;
#pragma unroll
  for (int i = 0; i < 16; ++i) { int f = (m[base + i] >= 1); fl |= f << i; cq += f; }
  __shared__ int s[256];
  s[t] = cq; __syncthreads();
  for (int off = 1; off < 256; off <<= 1) {
    int v = (t >= off) ? s[t - off] : 0;
    __syncthreads(); s[t] += v; __syncthreads();
  }
  int total = s[255];
  int qp = s[t] - cq;
  int kp = base - qp;
  for (int i = 0; i < 16; ++i) {
    int j = base + i;
    if ((fl >> i) & 1) qlist[b * HW + qp++] = j;
    else               klist[b * HW + kp++] = j;
    srcmap[b * HW + j] = -1;
  }
  if (t == 0) { qcnt[b] = total; kcnt[b] = HW - total; }
}

// --- K3: pack normalized keys. Layout: kpack[((b*C2+c)*4 + slice)*1024 + t*8 + r]
//     holds key (packed idx) kk = slice*1024 + r*128 + t, so pass1 thread t reads
//     its 8 keys per channel as two contiguous float4s.
__global__ void pack_kernel(const float* __restrict__ in, const float* __restrict__ inv,
                            const int* __restrict__ kcnt, const int* __restrict__ klist,
                            float* __restrict__ kpack) {
  int x = blockIdx.x * 256 + threadIdx.x;   // [0, 512): t in [0,128), slice in [0,4)
  int t = x & (BT - 1), sl = x >> 7;
  int c = blockIdx.y, b = blockIdx.z;
  int kc = kcnt[b];
  const float* lat = in + ((size_t)b * 512 + C2 + c) * HW;
  const float* dn = inv + b * HW;
  float v[NK];
#pragma unroll
  for (int r = 0; r < NK; ++r) {
    int jj = (sl << 10) + (r << 7) + t;
    float val = 0.f;
    if (jj < kc) { int j = klist[b * HW + jj]; val = lat[j] * dn[j]; }
    v[r] = val;
  }
  float* dst = kpack + (((size_t)(b * C2 + c) * 4 + sl) << 10) + t * NK;
  *(float4*)dst = make_float4(v[0], v[1], v[2], v[3]);
  *(float4*)(dst + 4) = make_float4(v[4], v[5], v[6], v[7]);
}

// --- K4: passthrough copy of channels [0,512) -------------------------------
__global__ void copy_kernel(const float4* __restrict__ in, float* __restrict__ out) {
  size_t idx = (size_t)blockIdx.x * 256 + threadIdx.x;  // 2^21 float4s
  int b = (int)(idx >> 19);
  size_t r = idx & 524287;
  float4 v = in[((size_t)b << 19) + r];
  ((float4*)(out + (size_t)b * 768 * HW))[r] = v;
}

// --- K5a: fused GEMM + per-slice argmax. Block: 16 queries x 1024-key slice.
// grid.x = slice*4 + b (16 combos; XCD-friendly), grid.y = qtile.
__global__ __launch_bounds__(BT, 3) void argmax_pass1(
    const float* __restrict__ in, const float* __restrict__ kpack,
    const int* __restrict__ qcnt, const int* __restrict__ kcnt,
    const int* __restrict__ qlist, unsigned long long* __restrict__ partials) {
  int combo = blockIdx.x;
  int b = combo & 3, sl = combo >> 2;
  int qtile = blockIdx.y;
  int nq_tot = qcnt[b], kc = kcnt[b];
  int qstart = qtile * TQ;
  if (qstart >= nq_tot || (sl << 10) >= kc) return;
  int nq = min(TQ, nq_tot - qstart);
  int t = threadIdx.x;

  __shared__ float qt_s[C2][TQ];   // 16 KB
  {
    int q = t & (TQ - 1), cr = t >> 4;   // cr in [0,8)
    int jq = (q < nq) ? qlist[b * HW + qstart + q] : 0;
    const float* src = in + ((size_t)b * 512 + C2) * HW + jq;
#pragma unroll
    for (int p = 0; p < 32; ++p) {
      int c = p * 8 + cr;
      qt_s[c][q] = (q < nq) ? src[(size_t)c * HW] : 0.f;
    }
  }
  __syncthreads();

  const float* kcol = kpack + (((size_t)b * C2 * 4 + sl) << 10) + t * NK;
  float acc[NK][TQ];
#pragma unroll
  for (int r = 0; r < NK; ++r)
#pragma unroll
    for (int q = 0; q < TQ; ++q) acc[r][q] = 0.f;

#pragma unroll 2
  for (int c = 0; c < C2; ++c) {
    const float* kp = kcol + c * 4096;
    float4 k0 = *(const float4*)kp;
    float4 k1 = *(const float4*)(kp + 4);
    float kv[NK] = {k0.x, k0.y, k0.z, k0.w, k1.x, k1.y, k1.z, k1.w};
#pragma unroll
    for (int qq = 0; qq < TQ; qq += 4) {
      float4 f = *(const float4*)&qt_s[c][qq];   // broadcast ds_read_b128
      float qv[4] = {f.x, f.y, f.z, f.w};
#pragma unroll
      for (int r = 0; r < NK; ++r)
#pragma unroll
        for (int i = 0; i < 4; ++i)
          acc[r][qq + i] = fmaf(kv[r], qv[i], acc[r][qq + i]);
    }
  }

  unsigned long long best[TQ];
#pragma unroll
  for (int q = 0; q < TQ; ++q) best[q] = 0ull;
#pragma unroll
  for (int r = 0; r < NK; ++r) {
    int kk = (sl << 10) + (r << 7) + t;
    if (kk < kc) {
#pragma unroll
      for (int q = 0; q < TQ; ++q) {
        unsigned long long pk =
            ((unsigned long long)ordf(acc[r][q]) << 32) | (unsigned)(0xFFFFFFFFu - (unsigned)kk);
        if (pk > best[q]) best[q] = pk;
      }
    }
  }

  __shared__ unsigned long long red[2][TQ];
  int lane = t & 63, wid = t >> 6;
#pragma unroll
  for (int q = 0; q < TQ; ++q) {
    unsigned long long v = best[q];
    for (int off = 32; off >= 1; off >>= 1) {
      unsigned long long o = shfl_down_u64(v, off);
      if (o > v) v = o;
    }
    if (lane == 0) red[wid][q] = v;
  }
  __syncthreads();
  if (t < TQ) {
    unsigned long long v = red[0][t];
    if (red[1][t] > v) v = red[1][t];
    partials[(((size_t)b * 4 + sl) * 256 + qtile) * TQ + t] = v;
  }
}

// --- K5b: reduce slices -> srcmap -------------------------------------------
__global__ void argmax_pass2(const unsigned long long* __restrict__ partials,
                             const int* __restrict__ qcnt, const int* __restrict__ kcnt,
                             const int* __restrict__ qlist, const int* __restrict__ klist,
                             int* __restrict__ srcmap) {
  int idx = blockIdx.x * 256 + threadIdx.x;  // [0, 16384)
  int b = idx >> 12, qpos = idx & (HW - 1);
  if (qpos >= qcnt[b]) return;
  int kc = kcnt[b];
  int ns = (kc + 1023) >> 10;
  int qtile = qpos >> 4, q = qpos & (TQ - 1);
  unsigned long long v = 0ull;
  for (int s = 0; s < ns; ++s) {
    unsigned long long p = partials[(((size_t)b * 4 + s) * 256 + qtile) * TQ + q];
    if (p > v) v = p;
  }
  if (!v) return;
  int kk = (int)(0xFFFFFFFFu - (unsigned)(v & 0xFFFFFFFFull));
  srcmap[b * HW + qlist[b * HW + qpos]] = klist[b * HW + kk];
}

// --- K6: shifted channels ----------------------------------------------------
__global__ void gather_kernel(const float* __restrict__ in, const int* __restrict__ srcmap,
                              float* __restrict__ out) {
  int idx = blockIdx.x * 256 + threadIdx.x;   // 2^22
  int j = idx & (HW - 1);
  int c = (idx >> 12) & 255;
  int b = idx >> 20;
  int s = srcmap[b * HW + j];
  float v = (s >= 0) ? in[((size_t)b * 512 + c) * HW + s] : 0.f;
  out[((size_t)b * 768 + 512 + c) * HW + j] = v;
}

extern "C" void kernel_launch(void* const* d_in, const int* in_sizes, int n_in,
                              void* d_out, int out_size, void* d_ws, size_t ws_size,
                              hipStream_t stream) {
  const float* in = (const float*)d_in[0];
  const int* mask = (const int*)d_in[1];
  float* out = (float*)d_out;

  // workspace layout (~19 MB)
  unsigned long long* partials = (unsigned long long*)d_ws;      // 4*4*256*16 u64 = 2 MB
  float* kpack = (float*)(partials + (size_t)BZd * 4 * 256 * TQ); // 4*256*4096 f32 = 16.8 MB
  float* inv = kpack + (size_t)BZd * C2 * HW;                     // 16384 f32
  int* qlist = (int*)(inv + BZd * HW);                            // 16384
  int* klist = qlist + BZd * HW;                                  // 16384
  int* srcmap = klist + BZd * HW;                                 // 16384
  int* qcnt = srcmap + BZd * HW;                                  // 4
  int* kcnt = qcnt + BZd;                                         // 4

  hipLaunchKernelGGL(inv_kernel, dim3(BZd * HW / 256), dim3(256), 0, stream, in, inv);
  hipLaunchKernelGGL(scan_kernel, dim3(BZd), dim3(256), 0, stream,
                     mask, qcnt, kcnt, qlist, klist, srcmap);
  hipLaunchKernelGGL(pack_kernel, dim3(2, C2, BZd), dim3(256), 0, stream,
                     in, inv, kcnt, klist, kpack);
  hipLaunchKernelGGL(copy_kernel, dim3(BZd * 512 * HW / 4 / 256), dim3(256), 0, stream,
                     (const float4*)in, out);
  hipLaunchKernelGGL(argmax_pass1, dim3(16, HW / TQ), dim3(BT), 0, stream,
                     in, kpack, qcnt, kcnt, qlist, partials);
  hipLaunchKernelGGL(argmax_pass2, dim3(BZd * HW / 256), dim3(256), 0, stream,
                     partials, qcnt, kcnt, qlist, klist, srcmap);
  hipLaunchKernelGGL(gather_kernel, dim3(BZd * C2 * HW / 256), dim3(256), 0, stream,
                     in, srcmap, out);
}

// Round 3
// 342.576 us; speedup vs baseline: 1.2875x; 1.0829x over previous
//
#include <hip/hip_runtime.h>

// InnerShiftTriple: bz=4, c=512 (c2=256), h=w=64 (hw=4096), fp32 in/out, int32 mask.
// out = concat([former, latter, shifted]); shifted[i] = former[argmax_j sim(i,j)]
// for masked i over non-masked keys j, cosine sim of "latter" features.
// Argmax invariant to query normalization -> only keys normalized.

#define HW 4096
#define C2 256
#define BZd 4
#define TQ 16
#define NK 4          // keys per thread in pass1 (one float4)
#define BT 128        // pass1 threads; slice = BT*NK = 512 keys
#define NSL 8         // 8 slices of 512 keys

__device__ __forceinline__ unsigned ordf(float f) {
  unsigned u = __float_as_uint(f);
  return (u & 0x80000000u) ? ~u : (u | 0x80000000u);
}

__device__ __forceinline__ unsigned long long shfl_down_u64(unsigned long long v, int off) {
  unsigned lo = (unsigned)v, hi = (unsigned)(v >> 32);
  lo = __shfl_down(lo, off, 64);
  hi = __shfl_down(hi, off, 64);
  return ((unsigned long long)hi << 32) | lo;
}

// --- K1: per-pixel inv-norm = 1/(sqrt(sum_c latter^2)+1e-8) ------------------
__global__ void inv_kernel(const float* __restrict__ in, float* __restrict__ inv) {
  int idx = blockIdx.x * 256 + threadIdx.x;     // [0, 16384)
  int b = idx >> 12, j = idx & (HW - 1);
  const float* p = in + ((size_t)b * 512 + C2) * HW + j;
  float ss = 0.f;
#pragma unroll 8
  for (int c = 0; c < C2; ++c) { float v = p[(size_t)c * HW]; ss = fmaf(v, v, ss); }
  inv[idx] = 1.0f / (sqrtf(ss) + 1e-8f);
}

// --- K2: ordered compaction of masked (query) / known (key) pixel indices ----
__global__ void scan_kernel(const int* __restrict__ mask, int* __restrict__ qcnt,
                            int* __restrict__ kcnt, int* __restrict__ qlist,
                            int* __restrict__ klist, int* __restrict__ srcmap) {
  int b = blockIdx.x, t = threadIdx.x;
  const int* m = mask + b * HW;
  int base = t * 16;
  int fl = 0, cq = 0;
#pragma unroll
  for (int i = 0; i < 16; ++i) { int f = (m[base + i] >= 1); fl |= f << i; cq += f; }
  __shared__ int s[256];
  s[t] = cq; __syncthreads();
  for (int off = 1; off < 256; off <<= 1) {
    int v = (t >= off) ? s[t - off] : 0;
    __syncthreads(); s[t] += v; __syncthreads();
  }
  int total = s[255];
  int qp = s[t] - cq;
  int kp = base - qp;
  for (int i = 0; i < 16; ++i) {
    int j = base + i;
    if ((fl >> i) & 1) qlist[b * HW + qp++] = j;
    else               klist[b * HW + kp++] = j;
    srcmap[b * HW + j] = -1;
  }
  if (t == 0) { qcnt[b] = total; kcnt[b] = HW - total; }
}

// --- K3: pack normalized keys.
// kpack[((b*C2+c)*NSL + sl)*512 + t*4 + r] holds key kk = sl*512 + r*128 + t,
// so pass1 thread t reads its 4 keys/channel as one contiguous float4.
__global__ void pack_kernel(const float* __restrict__ in, const float* __restrict__ inv,
                            const int* __restrict__ kcnt, const int* __restrict__ klist,
                            float* __restrict__ kpack) {
  int x = blockIdx.x * 256 + threadIdx.x;   // [0, 1024): t in [0,128), sl in [0,8)
  int t = x & (BT - 1), sl = x >> 7;
  int c = blockIdx.y, b = blockIdx.z;
  int kc = kcnt[b];
  const float* lat = in + ((size_t)b * 512 + C2 + c) * HW;
  const float* dn = inv + b * HW;
  float v[NK];
#pragma unroll
  for (int r = 0; r < NK; ++r) {
    int jj = (sl << 9) + (r << 7) + t;
    float val = 0.f;
    if (jj < kc) { int j = klist[b * HW + jj]; val = lat[j] * dn[j]; }
    v[r] = val;
  }
  float* dst = kpack + ((((size_t)(b * C2 + c) * NSL) + sl) << 9) + t * NK;
  *(float4*)dst = make_float4(v[0], v[1], v[2], v[3]);
}

// --- K4: fused GEMM + per-slice argmax. 16 queries (LDS) x 512-key slice.
// grid.x = sl*4 + b (32 combos, XCD-friendly), grid.y = qtile.
__global__ __launch_bounds__(BT, 4) void argmax_pass1(
    const float* __restrict__ in, const float* __restrict__ kpack,
    const int* __restrict__ qcnt, const int* __restrict__ kcnt,
    const int* __restrict__ qlist, unsigned long long* __restrict__ partials) {
  int combo = blockIdx.x;
  int b = combo & 3, sl = combo >> 2;
  int qtile = blockIdx.y;
  int nq_tot = qcnt[b], kc = kcnt[b];
  int qstart = qtile * TQ;
  if (qstart >= nq_tot || (sl << 9) >= kc) return;
  int nq = min(TQ, nq_tot - qstart);
  int t = threadIdx.x;

  __shared__ float qt_s[C2][TQ];   // 16 KB
  {
    int q = t & (TQ - 1), cr = t >> 4;   // cr in [0,8)
    int jq = qlist[b * HW + qstart + ((q < nq) ? q : 0)];
    const float* src = in + ((size_t)b * 512 + C2) * HW + jq;
#pragma unroll
    for (int p = 0; p < 32; ++p) {
      int c = p * 8 + cr;
      qt_s[c][q] = (q < nq) ? src[(size_t)c * HW] : 0.f;
    }
  }
  __syncthreads();

  const float* kcol = kpack + ((((size_t)b * C2) * NSL + sl) << 9) + t * NK;
  float acc[NK][TQ];
#pragma unroll
  for (int r = 0; r < NK; ++r)
#pragma unroll
    for (int q = 0; q < TQ; ++q) acc[r][q] = 0.f;

#pragma unroll 2
  for (int c = 0; c < C2; ++c) {
    float4 k = *(const float4*)(kcol + (size_t)c * (NSL * 512));
    float kv[NK] = {k.x, k.y, k.z, k.w};
#pragma unroll
    for (int qq = 0; qq < TQ; qq += 4) {
      float4 f = *(const float4*)&qt_s[c][qq];   // broadcast ds_read_b128
#pragma unroll
      for (int r = 0; r < NK; ++r) {
        acc[r][qq + 0] = fmaf(kv[r], f.x, acc[r][qq + 0]);
        acc[r][qq + 1] = fmaf(kv[r], f.y, acc[r][qq + 1]);
        acc[r][qq + 2] = fmaf(kv[r], f.z, acc[r][qq + 2]);
        acc[r][qq + 3] = fmaf(kv[r], f.w, acc[r][qq + 3]);
      }
    }
  }

  unsigned long long best[TQ];
#pragma unroll
  for (int q = 0; q < TQ; ++q) best[q] = 0ull;
#pragma unroll
  for (int r = 0; r < NK; ++r) {
    int kk = (sl << 9) + (r << 7) + t;
    if (kk < kc) {
#pragma unroll
      for (int q = 0; q < TQ; ++q) {
        unsigned long long pk =
            ((unsigned long long)ordf(acc[r][q]) << 32) | (unsigned)(0xFFFFFFFFu - (unsigned)kk);
        if (pk > best[q]) best[q] = pk;
      }
    }
  }

  __shared__ unsigned long long red[2][TQ];
  int lane = t & 63, wid = t >> 6;
#pragma unroll
  for (int q = 0; q < TQ; ++q) {
    unsigned long long v = best[q];
    for (int off = 32; off >= 1; off >>= 1) {
      unsigned long long o = shfl_down_u64(v, off);
      if (o > v) v = o;
    }
    if (lane == 0) red[wid][q] = v;
  }
  __syncthreads();
  if (t < TQ) {
    unsigned long long v = red[0][t];
    if (red[1][t] > v) v = red[1][t];
    partials[(((size_t)b * NSL + sl) * 256 + qtile) * TQ + t] = v;
  }
}

// --- K5: reduce slices -> srcmap --------------------------------------------
__global__ void argmax_pass2(const unsigned long long* __restrict__ partials,
                             const int* __restrict__ qcnt, const int* __restrict__ kcnt,
                             const int* __restrict__ qlist, const int* __restrict__ klist,
                             int* __restrict__ srcmap) {
  int idx = blockIdx.x * 256 + threadIdx.x;  // [0, 16384)
  int b = idx >> 12, qpos = idx & (HW - 1);
  if (qpos >= qcnt[b]) return;
  int kc = kcnt[b];
  int ns = (kc + 511) >> 9;
  int qtile = qpos >> 4, q = qpos & (TQ - 1);
  unsigned long long v = 0ull;
  for (int s = 0; s < ns; ++s) {
    unsigned long long p = partials[(((size_t)b * NSL + s) * 256 + qtile) * TQ + q];
    if (p > v) v = p;
  }
  if (!v) return;
  int kk = (int)(0xFFFFFFFFu - (unsigned)(v & 0xFFFFFFFFull));
  srcmap[b * HW + qlist[b * HW + qpos]] = klist[b * HW + kk];
}

// --- K6: all outputs: passthrough copy (float4) + shifted gather -------------
__global__ void out_kernel(const float* __restrict__ in, const int* __restrict__ srcmap,
                           float* __restrict__ out) {
  int bid = blockIdx.x;
  if (bid < 8192) {
    // channels [0,512): 2^21 float4s
    size_t idx = (size_t)bid * 256 + threadIdx.x;
    int b = (int)(idx >> 19);
    size_t r = idx & 524287;
    float4 v = ((const float4*)in)[((size_t)b << 19) + r];
    ((float4*)(out + (size_t)b * 768 * HW))[r] = v;
  } else {
    // channels [512,768): gather per element
    int idx = (bid - 8192) * 256 + threadIdx.x;   // [0, 2^22)
    int j = idx & (HW - 1);
    int c = (idx >> 12) & 255;
    int b = idx >> 20;
    int s = srcmap[b * HW + j];
    float v = (s >= 0) ? in[((size_t)b * 512 + c) * HW + s] : 0.f;
    out[((size_t)b * 768 + 512 + c) * HW + j] = v;
  }
}

extern "C" void kernel_launch(void* const* d_in, const int* in_sizes, int n_in,
                              void* d_out, int out_size, void* d_ws, size_t ws_size,
                              hipStream_t stream) {
  const float* in = (const float*)d_in[0];
  const int* mask = (const int*)d_in[1];
  float* out = (float*)d_out;

  // workspace layout (~21.3 MB)
  unsigned long long* partials = (unsigned long long*)d_ws;        // 4*8*256*16 u64 = 4 MB
  float* kpack = (float*)(partials + (size_t)BZd * NSL * 256 * TQ); // 16.8 MB
  float* inv = kpack + (size_t)BZd * C2 * HW;                       // 64 KB
  int* qlist = (int*)(inv + BZd * HW);                              // 64 KB
  int* klist = qlist + BZd * HW;                                    // 64 KB
  int* srcmap = klist + BZd * HW;                                   // 64 KB
  int* qcnt = srcmap + BZd * HW;                                    // 16 B
  int* kcnt = qcnt + BZd;                                           // 16 B

  hipLaunchKernelGGL(inv_kernel, dim3(BZd * HW / 256), dim3(256), 0, stream, in, inv);
  hipLaunchKernelGGL(scan_kernel, dim3(BZd), dim3(256), 0, stream,
                     mask, qcnt, kcnt, qlist, klist, srcmap);
  hipLaunchKernelGGL(pack_kernel, dim3(4, C2, BZd), dim3(256), 0, stream,
                     in, inv, kcnt, klist, kpack);
  hipLaunchKernelGGL(argmax_pass1, dim3(32, HW / TQ), dim3(BT), 0, stream,
                     in, kpack, qcnt, kcnt, qlist, partials);
  hipLaunchKernelGGL(argmax_pass2, dim3(BZd * HW / 256), dim3(256), 0, stream,
                     partials, qcnt, kcnt, qlist, klist, srcmap);
  hipLaunchKernelGGL(out_kernel, dim3(8192 + 16384), dim3(256), 0, stream,
                     in, srcmap, out);
}

// Round 4
// 294.311 us; speedup vs baseline: 1.4987x; 1.1640x over previous
//
#include <hip/hip_runtime.h>

// InnerShiftTriple: bz=4, c=512 (c2=256), h=w=64 (hw=4096), fp32 in/out, int32 mask.
// out = concat([former, latter, shifted]); shifted[i] = former[argmax_j sim(i,j)]
// for masked i over non-masked keys j, cosine sim of "latter" features.
// Argmax invariant to query normalization -> only keys normalized.

#define HW 4096
#define C2 256
#define BZd 4
#define TQ 16
#define NK 4          // keys per thread in pass1 (one float4)
#define BT 256        // pass1 threads; slice = BT*NK = 1024 keys
#define NSL 4         // 4 slices of 1024 keys

__device__ __forceinline__ unsigned ordf(float f) {
  unsigned u = __float_as_uint(f);
  return (u & 0x80000000u) ? ~u : (u | 0x80000000u);
}

__device__ __forceinline__ unsigned long long shfl_down_u64(unsigned long long v, int off) {
  unsigned lo = (unsigned)v, hi = (unsigned)(v >> 32);
  lo = __shfl_down(lo, off, 64);
  hi = __shfl_down(hi, off, 64);
  return ((unsigned long long)hi << 32) | lo;
}

// --- K1: per-pixel inv-norm = 1/(sqrt(sum_c latter^2)+1e-8) ------------------
__global__ void inv_kernel(const float* __restrict__ in, float* __restrict__ inv) {
  int idx = blockIdx.x * 256 + threadIdx.x;     // [0, 16384)
  int b = idx >> 12, j = idx & (HW - 1);
  const float* p = in + ((size_t)b * 512 + C2) * HW + j;
  float ss = 0.f;
#pragma unroll 8
  for (int c = 0; c < C2; ++c) { float v = p[(size_t)c * HW]; ss = fmaf(v, v, ss); }
  inv[idx] = 1.0f / (sqrtf(ss) + 1e-8f);
}

// --- K2: ordered compaction of masked (query) / known (key) pixel indices ----
__global__ void scan_kernel(const int* __restrict__ mask, int* __restrict__ qcnt,
                            int* __restrict__ kcnt, int* __restrict__ qlist,
                            int* __restrict__ klist, int* __restrict__ srcmap) {
  int b = blockIdx.x, t = threadIdx.x;
  const int* m = mask + b * HW;
  int base = t * 16;
  int fl = 0, cq = 0;
#pragma unroll
  for (int i = 0; i < 16; ++i) { int f = (m[base + i] >= 1); fl |= f << i; cq += f; }
  __shared__ int s[256];
  s[t] = cq; __syncthreads();
  for (int off = 1; off < 256; off <<= 1) {
    int v = (t >= off) ? s[t - off] : 0;
    __syncthreads(); s[t] += v; __syncthreads();
  }
  int total = s[255];
  int qp = s[t] - cq;
  int kp = base - qp;
  for (int i = 0; i < 16; ++i) {
    int j = base + i;
    if ((fl >> i) & 1) qlist[b * HW + qp++] = j;
    else               klist[b * HW + kp++] = j;
    srcmap[b * HW + j] = -1;
  }
  if (t == 0) { qcnt[b] = total; kcnt[b] = HW - total; }
}

// --- K3: pack normalized keys + un-normalized queries.
// kpack[((b*C2+c)*NSL + sl)*1024 + t*4 + r] holds key kk = sl*1024 + r*256 + t
// (pass1 thread t reads its 4 keys/channel as one float4).
// qpack[(b*C2+c)*HW + jj] holds query at packed position jj (0 beyond qcnt).
__global__ void pack_kernel(const float* __restrict__ in, const float* __restrict__ inv,
                            const int* __restrict__ qcnt, const int* __restrict__ kcnt,
                            const int* __restrict__ qlist, const int* __restrict__ klist,
                            float* __restrict__ kpack, float* __restrict__ qpack) {
  int t = threadIdx.x;
  int x = blockIdx.x;           // [0,8): 0..3 key slices, 4..7 query chunks
  int c = blockIdx.y, b = blockIdx.z;
  const float* lat = in + ((size_t)b * 512 + C2 + c) * HW;
  if (x < NSL) {
    int sl = x, kc = kcnt[b];
    const float* dn = inv + b * HW;
    float v[NK];
#pragma unroll
    for (int r = 0; r < NK; ++r) {
      int jj = (sl << 10) + (r << 8) + t;
      float val = 0.f;
      if (jj < kc) { int j = klist[b * HW + jj]; val = lat[j] * dn[j]; }
      v[r] = val;
    }
    float* dst = kpack + ((((size_t)(b * C2 + c) * NSL) + sl) << 10) + t * NK;
    *(float4*)dst = make_float4(v[0], v[1], v[2], v[3]);
  } else {
    int qc = x - NSL, nq = qcnt[b];
    float* dst = qpack + ((size_t)(b * C2 + c)) * HW;
#pragma unroll
    for (int r = 0; r < NK; ++r) {
      int jj = (qc << 10) + (r << 8) + t;
      float val = 0.f;
      if (jj < nq) val = lat[qlist[b * HW + jj]];
      dst[jj] = val;
    }
  }
}

// --- K4: fused GEMM + per-slice argmax. 16 queries (LDS) x 1024-key slice.
// grid.x = qtile, grid.y = sl*4 + b.
__global__ __launch_bounds__(BT, 4) void argmax_pass1(
    const float* __restrict__ qpack, const float* __restrict__ kpack,
    const int* __restrict__ qcnt, const int* __restrict__ kcnt,
    unsigned long long* __restrict__ partials) {
  int combo = blockIdx.y;
  int b = combo & 3, sl = combo >> 2;
  int qtile = blockIdx.x;
  int nq_tot = qcnt[b], kc = kcnt[b];
  int qstart = qtile * TQ;
  if (qstart >= nq_tot || (sl << 10) >= kc) return;
  int t = threadIdx.x;

  __shared__ float qt_s[C2][TQ];   // 16 KB
  {
    const float* qb = qpack + ((size_t)b * C2) * HW + qstart;
#pragma unroll
    for (int p = 0; p < 4; ++p) {
      int idx4 = p * 256 + t;        // [0,1024)
      int c = idx4 >> 2, qg = idx4 & 3;
      float4 v = *(const float4*)(qb + (size_t)c * HW + qg * 4);
      *(float4*)&qt_s[c][qg * 4] = v;
    }
  }
  __syncthreads();

  const float* kcol = kpack + ((((size_t)b * C2) * NSL + sl) << 10) + t * NK;
  float acc[NK][TQ];
#pragma unroll
  for (int r = 0; r < NK; ++r)
#pragma unroll
    for (int q = 0; q < TQ; ++q) acc[r][q] = 0.f;

  // rotating depth-2 prefetch of the key float4 (stride NSL*1024 floats per c)
  float4 k0 = *(const float4*)(kcol);
  float4 k1 = *(const float4*)(kcol + (size_t)(NSL << 10));
  for (int c = 0; c < C2; ++c) {
    float4 kq = k0;
    k0 = k1;
    int cp = c + 2; if (cp > C2 - 1) cp = C2 - 1;
    k1 = *(const float4*)(kcol + (size_t)cp * (NSL << 10));
    float kv[NK] = {kq.x, kq.y, kq.z, kq.w};
#pragma unroll
    for (int qq = 0; qq < TQ; qq += 4) {
      float4 f = *(const float4*)&qt_s[c][qq];   // broadcast ds_read_b128
#pragma unroll
      for (int r = 0; r < NK; ++r) {
        acc[r][qq + 0] = fmaf(kv[r], f.x, acc[r][qq + 0]);
        acc[r][qq + 1] = fmaf(kv[r], f.y, acc[r][qq + 1]);
        acc[r][qq + 2] = fmaf(kv[r], f.z, acc[r][qq + 2]);
        acc[r][qq + 3] = fmaf(kv[r], f.w, acc[r][qq + 3]);
      }
    }
  }

  unsigned long long best[TQ];
#pragma unroll
  for (int q = 0; q < TQ; ++q) best[q] = 0ull;
#pragma unroll
  for (int r = 0; r < NK; ++r) {
    int kk = (sl << 10) + (r << 8) + t;
    if (kk < kc) {
#pragma unroll
      for (int q = 0; q < TQ; ++q) {
        unsigned long long pk =
            ((unsigned long long)ordf(acc[r][q]) << 32) | (unsigned)(0xFFFFFFFFu - (unsigned)kk);
        if (pk > best[q]) best[q] = pk;
      }
    }
  }

  __shared__ unsigned long long red[4][TQ];
  int lane = t & 63, wid = t >> 6;
#pragma unroll
  for (int q = 0; q < TQ; ++q) {
    unsigned long long v = best[q];
    for (int off = 32; off >= 1; off >>= 1) {
      unsigned long long o = shfl_down_u64(v, off);
      if (o > v) v = o;
    }
    if (lane == 0) red[wid][q] = v;
  }
  __syncthreads();
  if (t < TQ) {
    unsigned long long v = red[0][t];
#pragma unroll
    for (int w = 1; w < 4; ++w) if (red[w][t] > v) v = red[w][t];
    partials[(((size_t)b * NSL + sl) * 256 + qtile) * TQ + t] = v;
  }
}

// --- K5: reduce slices -> srcmap --------------------------------------------
__global__ void argmax_pass2(const unsigned long long* __restrict__ partials,
                             const int* __restrict__ qcnt, const int* __restrict__ kcnt,
                             const int* __restrict__ qlist, const int* __restrict__ klist,
                             int* __restrict__ srcmap) {
  int idx = blockIdx.x * 256 + threadIdx.x;  // [0, 16384)
  int b = idx >> 12, qpos = idx & (HW - 1);
  if (qpos >= qcnt[b]) return;
  int kc = kcnt[b];
  int ns = (kc + 1023) >> 10;
  int qtile = qpos >> 4, q = qpos & (TQ - 1);
  unsigned long long v = 0ull;
  for (int s = 0; s < ns; ++s) {
    unsigned long long p = partials[(((size_t)b * NSL + s) * 256 + qtile) * TQ + q];
    if (p > v) v = p;
  }
  if (!v) return;
  int kk = (int)(0xFFFFFFFFu - (unsigned)(v & 0xFFFFFFFFull));
  srcmap[b * HW + qlist[b * HW + qpos]] = klist[b * HW + kk];
}

// --- K6: all outputs: passthrough copy (float4) + shifted gather -------------
__global__ void out_kernel(const float* __restrict__ in, const int* __restrict__ srcmap,
                           float* __restrict__ out) {
  int bid = blockIdx.x;
  if (bid < 8192) {
    size_t idx = (size_t)bid * 256 + threadIdx.x;
    int b = (int)(idx >> 19);
    size_t r = idx & 524287;
    float4 v = ((const float4*)in)[((size_t)b << 19) + r];
    ((float4*)(out + (size_t)b * 768 * HW))[r] = v;
  } else {
    int idx = (bid - 8192) * 256 + threadIdx.x;   // [0, 2^22)
    int j = idx & (HW - 1);
    int c = (idx >> 12) & 255;
    int b = idx >> 20;
    int s = srcmap[b * HW + j];
    float v = (s >= 0) ? in[((size_t)b * 512 + c) * HW + s] : 0.f;
    out[((size_t)b * 768 + 512 + c) * HW + j] = v;
  }
}

extern "C" void kernel_launch(void* const* d_in, const int* in_sizes, int n_in,
                              void* d_out, int out_size, void* d_ws, size_t ws_size,
                              hipStream_t stream) {
  const float* in = (const float*)d_in[0];
  const int* mask = (const int*)d_in[1];
  float* out = (float*)d_out;

  // workspace layout (~34.5 MB)
  unsigned long long* partials = (unsigned long long*)d_ws;         // 4*4*256*16 u64 = 512 KB
  float* kpack = (float*)(partials + (size_t)BZd * NSL * 256 * TQ); // 16.8 MB
  float* qpack = kpack + (size_t)BZd * C2 * HW;                      // 16.8 MB
  float* inv = qpack + (size_t)BZd * C2 * HW;                        // 64 KB
  int* qlist = (int*)(inv + BZd * HW);                               // 64 KB
  int* klist = qlist + BZd * HW;                                     // 64 KB
  int* srcmap = klist + BZd * HW;                                    // 64 KB
  int* qcnt = srcmap + BZd * HW;                                     // 16 B
  int* kcnt = qcnt + BZd;                                            // 16 B

  hipLaunchKernelGGL(inv_kernel, dim3(BZd * HW / 256), dim3(256), 0, stream, in, inv);
  hipLaunchKernelGGL(scan_kernel, dim3(BZd), dim3(256), 0, stream,
                     mask, qcnt, kcnt, qlist, klist, srcmap);
  hipLaunchKernelGGL(pack_kernel, dim3(8, C2, BZd), dim3(256), 0, stream,
                     in, inv, qcnt, kcnt, qlist, klist, kpack, qpack);
  hipLaunchKernelGGL(argmax_pass1, dim3(256, NSL * BZd), dim3(BT), 0, stream,
                     qpack, kpack, qcnt, kcnt, partials);
  hipLaunchKernelGGL(argmax_pass2, dim3(BZd * HW / 256), dim3(256), 0, stream,
                     partials, qcnt, kcnt, qlist, klist, srcmap);
  hipLaunchKernelGGL(out_kernel, dim3(8192 + 16384), dim3(256), 0, stream,
                     in, srcmap, out);
}

// Round 5
// 275.519 us; speedup vs baseline: 1.6009x; 1.0682x over previous
//
#include <hip/hip_runtime.h>

// InnerShiftTriple: bz=4, c=512 (c2=256), h=w=64 (hw=4096), fp32 in/out, int32 mask.
// out = concat([former, latter, shifted]); shifted[i] = former[argmax_j sim(i,j)]
// for masked i over non-masked keys j, cosine sim of "latter" features.
// Argmax invariant to query normalization -> only keys normalized.
// Pass1 strategy: queries are wave-uniform -> SGPR broadcast via scalar loads
// (no LDS in the hot loop); keys stream from L2 as one float4/thread/channel.

#define HW 4096
#define C2 256
#define BZd 4
#define TQ 32         // queries per block (SGPR-broadcast)
#define NK 4          // keys per thread (one float4)
#define BT 256        // slice = BT*NK = 1024 keys
#define NSL 4         // up to 4 slices of 1024 keys
#define QT_MAX 128    // HW/TQ

__device__ __forceinline__ unsigned ordf(float f) {
  unsigned u = __float_as_uint(f);
  return (u & 0x80000000u) ? ~u : (u | 0x80000000u);
}

__device__ __forceinline__ unsigned long long shfl_down_u64(unsigned long long v, int off) {
  unsigned lo = (unsigned)v, hi = (unsigned)(v >> 32);
  lo = __shfl_down(lo, off, 64);
  hi = __shfl_down(hi, off, 64);
  return ((unsigned long long)hi << 32) | lo;
}

// --- K1: fused inv-norm (blocks 0..63) + mask compaction (blocks 64..67) -----
__global__ void prep_kernel(const float* __restrict__ in, const int* __restrict__ mask,
                            float* __restrict__ inv, int* __restrict__ qcnt,
                            int* __restrict__ kcnt, int* __restrict__ qlist,
                            int* __restrict__ klist, int* __restrict__ srcmap) {
  __shared__ int s[256];
  int bid = blockIdx.x, t = threadIdx.x;
  if (bid < 64) {
    int idx = bid * 256 + t;                  // [0, 16384)
    int b = idx >> 12, j = idx & (HW - 1);
    const float* p = in + ((size_t)b * 512 + C2) * HW + j;
    float ss = 0.f;
#pragma unroll 8
    for (int c = 0; c < C2; ++c) { float v = p[(size_t)c * HW]; ss = fmaf(v, v, ss); }
    inv[idx] = 1.0f / (sqrtf(ss) + 1e-8f);
  } else {
    int b = bid - 64;
    const int* m = mask + b * HW;
    int base = t * 16;
    int fl = 0, cq = 0;
#pragma unroll
    for (int i = 0; i < 16; ++i) { int f = (m[base + i] >= 1); fl |= f << i; cq += f; }
    s[t] = cq; __syncthreads();
    for (int off = 1; off < 256; off <<= 1) {
      int v = (t >= off) ? s[t - off] : 0;
      __syncthreads(); s[t] += v; __syncthreads();
    }
    int total = s[255];
    int qp = s[t] - cq;
    int kp = base - qp;
    for (int i = 0; i < 16; ++i) {
      int j = base + i;
      if ((fl >> i) & 1) qlist[b * HW + qp++] = j;
      else               klist[b * HW + kp++] = j;
      srcmap[b * HW + j] = -1;
    }
    if (t == 0) { qcnt[b] = total; kcnt[b] = HW - total; }
  }
}

// --- K2: pack normalized keys + un-normalized queries.
// kpack[((b*C2+c)*NSL + sl)*1024 + t*4 + r] holds key kk = sl*1024 + r*256 + t.
// qpack[(b*C2+c)*HW + jj] holds query at packed position jj (0 beyond qcnt).
__global__ void pack_kernel(const float* __restrict__ in, const float* __restrict__ inv,
                            const int* __restrict__ qcnt, const int* __restrict__ kcnt,
                            const int* __restrict__ qlist, const int* __restrict__ klist,
                            float* __restrict__ kpack, float* __restrict__ qpack) {
  int t = threadIdx.x;
  int x = blockIdx.x;           // [0,8): 0..3 key slices, 4..7 query chunks
  int c = blockIdx.y, b = blockIdx.z;
  const float* lat = in + ((size_t)b * 512 + C2 + c) * HW;
  if (x < NSL) {
    int sl = x, kc = kcnt[b];
    const float* dn = inv + b * HW;
    float v[NK];
#pragma unroll
    for (int r = 0; r < NK; ++r) {
      int jj = (sl << 10) + (r << 8) + t;
      float val = 0.f;
      if (jj < kc) { int j = klist[b * HW + jj]; val = lat[j] * dn[j]; }
      v[r] = val;
    }
    float* dst = kpack + ((((size_t)(b * C2 + c) * NSL) + sl) << 10) + t * NK;
    *(float4*)dst = make_float4(v[0], v[1], v[2], v[3]);
  } else {
    int qc = x - NSL, nq = qcnt[b];
    float* dst = qpack + ((size_t)(b * C2 + c)) * HW;
#pragma unroll
    for (int r = 0; r < NK; ++r) {
      int jj = (qc << 10) + (r << 8) + t;
      float val = 0.f;
      if (jj < nq) val = lat[qlist[b * HW + jj]];
      dst[jj] = val;
    }
  }
}

// --- K3: fused GEMM + per-slice argmax. 32 queries (SGPR) x 1024-key slice.
__global__ __launch_bounds__(BT, 3) void argmax_pass1(
    const float* __restrict__ qpack, const float* __restrict__ kpack,
    const int* __restrict__ qcnt, const int* __restrict__ kcnt,
    unsigned long long* __restrict__ partials) {
  int combo = blockIdx.y;
  int b = combo & 3, sl = combo >> 2;
  int qtile = blockIdx.x;
  int nq_tot = qcnt[b], kc = kcnt[b];
  int qstart = qtile * TQ;
  if (qstart >= nq_tot || (sl << 10) >= kc) return;
  int t = threadIdx.x;

  // wave-uniform query base -> scalar loads (SGPR broadcast operands)
  const float* qb = qpack + ((size_t)b * C2) * HW + qstart;
  const float* kcol = kpack + ((((size_t)b * C2) * NSL + sl) << 10) + t * NK;

  float acc[NK][TQ];
#pragma unroll
  for (int r = 0; r < NK; ++r)
#pragma unroll
    for (int q = 0; q < TQ; ++q) acc[r][q] = 0.f;

  // rotating depth-2 prefetch of the key float4 (stride NSL*1024 floats per c)
  float4 k0 = *(const float4*)(kcol);
  float4 k1 = *(const float4*)(kcol + (size_t)(NSL << 10));
#pragma unroll 2
  for (int c = 0; c < C2; ++c) {
    float4 kq = k0;
    k0 = k1;
    int cp = c + 2; if (cp > C2 - 1) cp = C2 - 1;
    k1 = *(const float4*)(kcol + (size_t)cp * (NSL << 10));
    float kv[NK] = {kq.x, kq.y, kq.z, kq.w};
    const float* qc_ = qb + (size_t)c * HW;   // uniform address
#pragma unroll
    for (int i = 0; i < TQ; ++i) {
      float qv = qc_[i];                       // s_load -> SGPR
#pragma unroll
      for (int r = 0; r < NK; ++r)
        acc[r][i] = fmaf(kv[r], qv, acc[r][i]);
    }
  }

  // per-q immediate reduction (no best[] array -> no register peak)
  __shared__ unsigned long long red[4][TQ];
  int lane = t & 63, wid = t >> 6;
#pragma unroll
  for (int q = 0; q < TQ; ++q) {
    unsigned long long v = 0ull;
#pragma unroll
    for (int r = 0; r < NK; ++r) {
      int kk = (sl << 10) + (r << 8) + t;
      if (kk < kc) {
        unsigned long long pk =
            ((unsigned long long)ordf(acc[r][q]) << 32) | (unsigned)(0xFFFFFFFFu - (unsigned)kk);
        if (pk > v) v = pk;
      }
    }
    for (int off = 32; off >= 1; off >>= 1) {
      unsigned long long o = shfl_down_u64(v, off);
      if (o > v) v = o;
    }
    if (lane == 0) red[wid][q] = v;
  }
  __syncthreads();
  if (t < TQ) {
    unsigned long long v = red[0][t];
#pragma unroll
    for (int w = 1; w < 4; ++w) if (red[w][t] > v) v = red[w][t];
    partials[(((size_t)b * NSL + sl) * QT_MAX + qtile) * TQ + t] = v;
  }
}

// --- K4: reduce slices -> srcmap --------------------------------------------
__global__ void argmax_pass2(const unsigned long long* __restrict__ partials,
                             const int* __restrict__ qcnt, const int* __restrict__ kcnt,
                             const int* __restrict__ qlist, const int* __restrict__ klist,
                             int* __restrict__ srcmap) {
  int idx = blockIdx.x * 256 + threadIdx.x;  // [0, 16384)
  int b = idx >> 12, qpos = idx & (HW - 1);
  if (qpos >= qcnt[b]) return;
  int kc = kcnt[b];
  int ns = (kc + 1023) >> 10;
  int qtile = qpos >> 5, q = qpos & (TQ - 1);
  unsigned long long v = 0ull;
  for (int s = 0; s < ns; ++s) {
    unsigned long long p = partials[(((size_t)b * NSL + s) * QT_MAX + qtile) * TQ + q];
    if (p > v) v = p;
  }
  if (!v) return;
  int kk = (int)(0xFFFFFFFFu - (unsigned)(v & 0xFFFFFFFFull));
  srcmap[b * HW + qlist[b * HW + qpos]] = klist[b * HW + kk];
}

// --- K5: all outputs: passthrough copy (float4) + shifted gather -------------
__global__ void out_kernel(const float* __restrict__ in, const int* __restrict__ srcmap,
                           float* __restrict__ out) {
  int bid = blockIdx.x;
  if (bid < 8192) {
    size_t idx = (size_t)bid * 256 + threadIdx.x;
    int b = (int)(idx >> 19);
    size_t r = idx & 524287;
    float4 v = ((const float4*)in)[((size_t)b << 19) + r];
    ((float4*)(out + (size_t)b * 768 * HW))[r] = v;
  } else {
    int idx = (bid - 8192) * 256 + threadIdx.x;   // [0, 2^22)
    int j = idx & (HW - 1);
    int c = (idx >> 12) & 255;
    int b = idx >> 20;
    int s = srcmap[b * HW + j];
    float v = (s >= 0) ? in[((size_t)b * 512 + c) * HW + s] : 0.f;
    out[((size_t)b * 768 + 512 + c) * HW + j] = v;
  }
}

extern "C" void kernel_launch(void* const* d_in, const int* in_sizes, int n_in,
                              void* d_out, int out_size, void* d_ws, size_t ws_size,
                              hipStream_t stream) {
  const float* in = (const float*)d_in[0];
  const int* mask = (const int*)d_in[1];
  float* out = (float*)d_out;

  // workspace layout (~34.5 MB)
  unsigned long long* partials = (unsigned long long*)d_ws;             // 4*4*128*32 u64 = 512 KB
  float* kpack = (float*)(partials + (size_t)BZd * NSL * QT_MAX * TQ);  // 16.8 MB
  float* qpack = kpack + (size_t)BZd * C2 * HW;                          // 16.8 MB
  float* inv = qpack + (size_t)BZd * C2 * HW;                            // 64 KB
  int* qlist = (int*)(inv + BZd * HW);                                   // 64 KB
  int* klist = qlist + BZd * HW;                                         // 64 KB
  int* srcmap = klist + BZd * HW;                                        // 64 KB
  int* qcnt = srcmap + BZd * HW;                                         // 16 B
  int* kcnt = qcnt + BZd;                                                // 16 B

  hipLaunchKernelGGL(prep_kernel, dim3(64 + BZd), dim3(256), 0, stream,
                     in, mask, inv, qcnt, kcnt, qlist, klist, srcmap);
  hipLaunchKernelGGL(pack_kernel, dim3(8, C2, BZd), dim3(256), 0, stream,
                     in, inv, qcnt, kcnt, qlist, klist, kpack, qpack);
  hipLaunchKernelGGL(argmax_pass1, dim3(QT_MAX, NSL * BZd), dim3(BT), 0, stream,
                     qpack, kpack, qcnt, kcnt, partials);
  hipLaunchKernelGGL(argmax_pass2, dim3(BZd * HW / 256), dim3(256), 0, stream,
                     partials, qcnt, kcnt, qlist, klist, srcmap);
  hipLaunchKernelGGL(out_kernel, dim3(8192 + 16384), dim3(256), 0, stream,
                     in, srcmap, out);
}